// Round 10
// baseline (854.176 us; speedup 1.0000x reference)
//
#include <hip/hip_runtime.h>
#include <math.h>
#include <stdint.h>

#define D_  1024
#define T_  1024
#define H_  8
#define HD_ 128
#define L_  4
#define V_  32000
#define M_  2048   // B*T

typedef __attribute__((ext_vector_type(4))) float f32x4;
typedef __attribute__((ext_vector_type(4))) short s16x4;
typedef __attribute__((ext_vector_type(8))) short s16x8;
typedef unsigned short u16;

__device__ __forceinline__ u16 f2bf(float f) {
  union { float f; uint32_t u; } c; c.f = f;
  uint32_t r = c.u + 0x7fffu + ((c.u >> 16) & 1u);   // RTN-even
  return (u16)(r >> 16);
}
__device__ __forceinline__ float bf2f(u16 h) {
  union { uint32_t u; float f; } c; c.u = ((uint32_t)h) << 16;
  return c.f;
}
__device__ __forceinline__ float gelu_f(float x) {
  return 0.5f * x * (1.0f + erff(x * 0.70710678118654752f));
}
__device__ __forceinline__ void nt_store(float* p, float v) {
  __builtin_nontemporal_store(v, p);
}

// async global->LDS, 16B per lane. LDS dest is wave-uniform base (HW adds
// lane*16); global ptr is per-lane. [guide §5, m97/m104]
__device__ __forceinline__ void gload16(const u16* g, u16* l) {
  __builtin_amdgcn_global_load_lds(
      (const __attribute__((address_space(1))) void*)(uintptr_t)g,
      (__attribute__((address_space(3))) void*)(uint32_t)(uintptr_t)l,
      16, 0, 0);
}

// ---------------------------------------------------------------------------
// Transpose-convert body: in f32 [R][C] -> out bf16 [C][R], one 64x64 tile.
// ---------------------------------------------------------------------------
__device__ __forceinline__ void convT_f32_tile(const float* __restrict__ in,
                                               u16* __restrict__ out,
                                               int ldin, int ldout,
                                               int c0, int r0,
                                               u16 (*tile)[72])
{
  const int t = threadIdx.x;
  const int rr = t >> 2, cs = (t & 3) << 4;
  u16 tmp[16];
  const float* p = in + (size_t)(r0 + rr) * ldin + c0 + cs;
#pragma unroll
  for (int q = 0; q < 4; ++q) {
    f32x4 v = *(const f32x4*)(p + q * 4);
#pragma unroll
    for (int j = 0; j < 4; ++j) tmp[q * 4 + j] = f2bf(v[j]);
  }
  *(s16x8*)&tile[rr][cs]     = *(const s16x8*)tmp;
  *(s16x8*)&tile[rr][cs + 8] = *(const s16x8*)(tmp + 8);
  __syncthreads();
  const int cr = t >> 2, rs = (t & 3) << 4;
  u16 o[16];
#pragma unroll
  for (int j = 0; j < 16; ++j) o[j] = tile[rs + j][cr];
  u16* op = out + (size_t)(c0 + cr) * ldout + r0 + rs;
  *(s16x8*)op       = *(const s16x8*)o;
  *(s16x8*)(op + 8) = *(const s16x8*)(o + 8);
}

// ---------------------------------------------------------------------------
// LayerNorm row body (+optional 4-way fc2-partial fold).
// ---------------------------------------------------------------------------
__device__ __forceinline__
void ln_row_body(int row, float* __restrict__ hbuf, const float* __restrict__ P,
                 const float* __restrict__ g, const float* __restrict__ b,
                 u16* __restrict__ y, int red, float* red_s)
{
  const int tid = threadIdx.x;
  const size_t i = (size_t)row * D_ + tid * 4;
  f32x4 v = *(const f32x4*)&hbuf[i];
  if (red) {
#pragma unroll
    for (int zp = 0; zp < 4; ++zp) {
      f32x4 p = *(const f32x4*)&P[(size_t)zp * M_ * D_ + i];
      v[0] += p[0]; v[1] += p[1]; v[2] += p[2]; v[3] += p[3];
    }
    *(f32x4*)&hbuf[i] = v;
  }
  float s  = v[0] + v[1] + v[2] + v[3];
  float s2 = v[0]*v[0] + v[1]*v[1] + v[2]*v[2] + v[3]*v[3];
#pragma unroll
  for (int off = 32; off > 0; off >>= 1) {
    s  += __shfl_xor(s, off);
    s2 += __shfl_xor(s2, off);
  }
  if ((tid & 63) == 0) { red_s[tid >> 6] = s; red_s[4 + (tid >> 6)] = s2; }
  __syncthreads();
  s  = red_s[0] + red_s[1] + red_s[2] + red_s[3];
  s2 = red_s[4] + red_s[5] + red_s[6] + red_s[7];
  const float mean = s * (1.0f / D_);
  const float var  = s2 * (1.0f / D_) - mean * mean;
  const float rs   = rsqrtf(var + 1e-5f);
  f32x4 gg = *(const f32x4*)&g[tid * 4];
  f32x4 bb = *(const f32x4*)&b[tid * 4];
  u16 o[4];
#pragma unroll
  for (int j = 0; j < 4; ++j) o[j] = f2bf((v[j] - mean) * rs * gg[j] + bb[j]);
  *(s16x4*)&y[i] = *(const s16x4*)o;
}

// Fused: ln1 (rows 0..2047, optional fc2-partial fold) + 4 weight transposes.
__global__ __launch_bounds__(256)
void conv4ln_kernel(const float* __restrict__ wqkv_l, const float* __restrict__ wo_l,
                    const float* __restrict__ wfc_l, const float* __restrict__ wfc2_l,
                    u16* __restrict__ Wq, u16* __restrict__ Wo,
                    u16* __restrict__ Wf1, u16* __restrict__ Wf2,
                    float* __restrict__ hbuf, const float* __restrict__ P,
                    const float* __restrict__ g, const float* __restrict__ b,
                    u16* __restrict__ y, int red)
{
  __shared__ __align__(16) u16 tile[64][72];
  int f = blockIdx.x;
  if (f < 2048) { ln_row_body(f, hbuf, P, g, b, y, red, (float*)tile); return; }
  f -= 2048;
  if (f < 768) {
    convT_f32_tile(wqkv_l, Wq, 3 * D_, D_, (f % 48) << 6, (f / 48) << 6, tile);
  } else if (f < 1024) {
    f -= 768;
    convT_f32_tile(wo_l, Wo, D_, D_, (f & 15) << 6, (f >> 4) << 6, tile);
  } else if (f < 2048) {
    f -= 1024;
    convT_f32_tile(wfc_l, Wf1, 4 * D_, D_, (f & 63) << 6, (f >> 6) << 6, tile);
  } else {
    f -= 2048;
    convT_f32_tile(wfc2_l, Wf2, D_, 4 * D_, (f & 15) << 6, (f >> 4) << 6, tile);
  }
}

// Fused: final LN (folds fc2 partials) + wout transpose (blocks 2048..10047).
__global__ __launch_bounds__(256)
void convwout_ln(const float* __restrict__ wout, u16* __restrict__ WoutT,
                 float* __restrict__ hbuf, const float* __restrict__ P,
                 const float* __restrict__ g, const float* __restrict__ b,
                 u16* __restrict__ y)
{
  __shared__ __align__(16) u16 tile[64][72];
  int f = blockIdx.x;
  if (f < 2048) { ln_row_body(f, hbuf, P, g, b, y, 1, (float*)tile); return; }
  f -= 2048;
  convT_f32_tile(wout, WoutT, V_, D_, (f % 500) << 6, (f / 500) << 6, tile);
}

// ln2 with 4-way wo-partial fold + bo: h += P0+P1+P2+P3+bo, then LN -> y.
__global__ __launch_bounds__(256)
void ln_fold4(float* __restrict__ hbuf, const float* __restrict__ P,
              const float* __restrict__ bo, const float* __restrict__ g,
              const float* __restrict__ b, u16* __restrict__ y)
{
  __shared__ float red_s[8];
  const int row = blockIdx.x, tid = threadIdx.x;
  const size_t i = (size_t)row * D_ + tid * 4;
  f32x4 v = *(const f32x4*)&hbuf[i];
  f32x4 bb4 = *(const f32x4*)&bo[tid * 4];
#pragma unroll
  for (int zp = 0; zp < 4; ++zp) {
    f32x4 p = *(const f32x4*)&P[(size_t)zp * M_ * D_ + i];
    v[0] += p[0]; v[1] += p[1]; v[2] += p[2]; v[3] += p[3];
  }
#pragma unroll
  for (int j = 0; j < 4; ++j) v[j] += bb4[j];
  *(f32x4*)&hbuf[i] = v;
  float s  = v[0] + v[1] + v[2] + v[3];
  float s2 = v[0]*v[0] + v[1]*v[1] + v[2]*v[2] + v[3]*v[3];
#pragma unroll
  for (int off = 32; off > 0; off >>= 1) {
    s  += __shfl_xor(s, off);
    s2 += __shfl_xor(s2, off);
  }
  if ((tid & 63) == 0) { red_s[tid >> 6] = s; red_s[4 + (tid >> 6)] = s2; }
  __syncthreads();
  s  = red_s[0] + red_s[1] + red_s[2] + red_s[3];
  s2 = red_s[4] + red_s[5] + red_s[6] + red_s[7];
  const float mean = s * (1.0f / D_);
  const float var  = s2 * (1.0f / D_) - mean * mean;
  const float rs   = rsqrtf(var + 1e-5f);
  f32x4 gg = *(const f32x4*)&g[tid * 4];
  f32x4 bbn = *(const f32x4*)&b[tid * 4];
  u16 o[4];
#pragma unroll
  for (int j = 0; j < 4; ++j) o[j] = f2bf((v[j] - mean) * rs * gg[j] + bbn[j]);
  *(s16x4*)&y[i] = *(const s16x4*)o;
}

// ---------------------------------------------------------------------------
// 256x128-tile 8-phase GEMM (gemm8n), KT parameterized (K = KT*64).
// Ledger (3 gloads/phase/wave): prologue stages t0{kh0,kh1}+t1{kh0} (9 loads),
// VM6 lands t0.kh0. Each phase stages one half-set 3-ahead; VM6 retires
// exactly the half-set the next phase reads. Tail: kt clamped to KT-1
// (redundant re-stage into WAR-safe dead slots keeps counts uniform).
// Verified by simulation for KT=16 (R7) and KT=4 (R10).
// VSPLIT: blocks with n0>=2048 write transposed to VtOut[b][col-2048][t].
// OUT: 0 bf16, 1 f32 (nontemporal). BIAS adds bias[col]. ACT = gelu.
// ---------------------------------------------------------------------------
template<int OUT, int ACT, int BIAS, int VSPLIT, int KT>
__device__ __forceinline__
void gemm8n_body(const u16* __restrict__ A, int lda,
                 const u16* __restrict__ Bw, int ldb,
                 const float* __restrict__ bias,
                 void* __restrict__ Cv, int ldc, int bx, int by,
                 u16* __restrict__ VtOut)
{
  const int m0 = bx << 8, n0 = by << 7;

  __shared__ __align__(16) u16 lds[49152];   // 96 KiB

  const int tid = threadIdx.x, lane = tid & 63, wave = tid >> 6;
  const int wm = wave >> 1, wn = wave & 1;
  const int l15 = lane & 15, l4 = lane >> 4;

  f32x4 acc[4][4];
  const f32x4 z4 = {0.f, 0.f, 0.f, 0.f};
#pragma unroll
  for (int i = 0; i < 4; ++i)
#pragma unroll
    for (int j = 0; j < 4; ++j) acc[i][j] = z4;

  // buf b at b*24576 (u16): A0 +0, A1 +8192, B0 +16384, B1 +20480
  auto stgA = [&](int buf, int kt, int kh) {
    kt = (kt < KT - 1) ? kt : (KT - 1);
    const int slot = buf * 24576 + kh * 8192;
#pragma unroll
    for (int r = 0; r < 2; ++r) {
      const int u = r * 512 + (wave << 6) + lane;
      const int rw = u >> 2, ks = u & 3;
      const int ksw = ks ^ ((rw >> 1) & 3);
      gload16(A + (size_t)(m0 + rw) * lda + (kt << 6) + (kh << 5) + (ksw << 3),
              &lds[slot + r * 4096 + (wave << 9)]);
    }
  };
  auto stgB = [&](int buf, int kt, int kh) {
    kt = (kt < KT - 1) ? kt : (KT - 1);
    const int slot = buf * 24576 + 16384 + kh * 4096;
    const int u = (wave << 6) + lane;
    const int rw = u >> 2, ks = u & 3;
    const int ksw = ks ^ ((rw >> 1) & 3);
    gload16(Bw + (size_t)(n0 + rw) * ldb + (kt << 6) + (kh << 5) + (ksw << 3),
            &lds[slot + (wave << 9)]);
  };

  s16x8 af[4], bfr[4];

#define LDABN(bb, kk)                                                         \
  {                                                                           \
    _Pragma("unroll") for (int f = 0; f < 4; ++f) {                           \
      const int rw = wm * 64 + f * 16 + l15;                                  \
      af[f] = *(const s16x8*)&lds[(bb) + (kk) * 8192 + rw * 32 +              \
                                  ((l4 ^ ((rw >> 1) & 3)) << 3)];             \
    }                                                                         \
    _Pragma("unroll") for (int f = 0; f < 4; ++f) {                           \
      const int rn = wn * 64 + f * 16 + l15;                                  \
      bfr[f] = *(const s16x8*)&lds[(bb) + 16384 + (kk) * 4096 + rn * 32 +     \
                                   ((l4 ^ ((rn >> 1) & 3)) << 3)];            \
    }                                                                         \
  }
#define MFMAN()                                                               \
  {                                                                           \
    __builtin_amdgcn_s_barrier();                                             \
    asm volatile("s_waitcnt lgkmcnt(0)" ::: "memory");                        \
    __builtin_amdgcn_sched_barrier(0);                                        \
    __builtin_amdgcn_s_setprio(1);                                            \
    _Pragma("unroll") for (int f = 0; f < 4; ++f)                             \
      _Pragma("unroll") for (int nf = 0; nf < 4; ++nf)                        \
        acc[f][nf] = __builtin_amdgcn_mfma_f32_16x16x32_bf16(                 \
            af[f], bfr[nf], acc[f][nf], 0, 0, 0);                             \
    __builtin_amdgcn_s_setprio(0);                                            \
  }
#define BARN() __builtin_amdgcn_s_barrier()
#define VM6()  asm volatile("s_waitcnt vmcnt(6)" ::: "memory")

  stgA(0, 0, 0); stgB(0, 0, 0);
  stgA(0, 0, 1); stgB(0, 0, 1);
  stgA(1, 1, 0); stgB(1, 1, 0);
  VM6();
  BARN();

  for (int i = 0; i < KT / 2; ++i) {
    const int t = 2 * i;
    LDABN(0, 0);
    stgA(1, t + 1, 1); stgB(1, t + 1, 1);
    MFMAN(); VM6(); BARN();
    LDABN(0, 1);
    stgA(0, t + 2, 0); stgB(0, t + 2, 0);
    MFMAN(); VM6(); BARN();
    LDABN(24576, 0);
    stgA(0, t + 2, 1); stgB(0, t + 2, 1);
    MFMAN(); VM6(); BARN();
    LDABN(24576, 1);
    stgA(1, t + 3, 0); stgB(1, t + 3, 0);
    MFMAN(); VM6(); BARN();
  }
#undef LDABN
#undef MFMAN
#undef BARN
#undef VM6

  // epilogue: col = l15, row = l4*4 + r per 16x16 fragment [m89]
  if (VSPLIT && n0 >= 2048) {
    // V-direct transpose: rows row0..+3 -> consecutive t in Vt[b][d][t]
#pragma unroll
    for (int mf = 0; mf < 4; ++mf) {
      const int row0 = m0 + wm * 64 + mf * 16 + l4 * 4;
      const int bb = row0 >> 10, t0 = row0 & 1023;
#pragma unroll
      for (int nf = 0; nf < 4; ++nf) {
        const int col = n0 + wn * 64 + nf * 16 + l15;
        const float bv = BIAS ? bias[col] : 0.0f;
        u16 o4[4];
#pragma unroll
        for (int r = 0; r < 4; ++r) o4[r] = f2bf(acc[mf][nf][r] + bv);
        *(s16x4*)&VtOut[((size_t)(bb << 10) + (col - 2048)) * 1024 + t0] =
            *(const s16x4*)o4;
      }
    }
    return;
  }
  float* Cf = (float*)Cv;
  u16*   Ch = (u16*)Cv;
#pragma unroll
  for (int mf = 0; mf < 4; ++mf) {
    const int row0 = m0 + wm * 64 + mf * 16 + l4 * 4;
#pragma unroll
    for (int nf = 0; nf < 4; ++nf) {
      const int col = n0 + wn * 64 + nf * 16 + l15;
      const float bv = BIAS ? bias[col] : 0.0f;
#pragma unroll
      for (int r = 0; r < 4; ++r) {
        float v = acc[mf][nf][r] + bv;
        if (ACT) v = gelu_f(v);
        const size_t idx = (size_t)(row0 + r) * ldc + col;
        if (OUT == 0) Ch[idx] = f2bf(v);
        else          nt_store(&Cf[idx], v);
      }
    }
  }
}

// qkv: M=2048 x N=3072 x K=1024; grid 192 (8M x 24N); V-cols -> Vt direct.
__global__ __launch_bounds__(512, 1)
void gemm8n_qkv(const u16* A, const u16* Bw, const float* bias, u16* C, u16* Vt) {
  int flat = blockIdx.x;
  int swz = (flat & 7) * 24 + (flat >> 3);
  gemm8n_body<0, 0, 1, 1, 16>(A, 1024, Bw, 1024, bias, C, 3 * D_,
                              swz & 7, swz >> 3, Vt);
}
// wo split-K=4: K-slice 256 (KT=4) -> f32 partial P[z]. Grid 256 (8x8x4).
__global__ __launch_bounds__(512, 1)
void gemm8n_wo(const u16* A, const u16* Bw, float* P) {
  int flat = blockIdx.x;
  int swz = (flat & 7) * 32 + (flat >> 3);
  const int bx = swz & 7, by = (swz >> 3) & 7, z = swz >> 6;
  gemm8n_body<1, 0, 0, 0, 4>(A + z * 256, 1024, Bw + z * 256, 1024, nullptr,
                             P + (size_t)z * M_ * D_, 1024, bx, by, nullptr);
}
// fc1: gelu(xn @ Wf1T) -> bf16 S. Grid 256 (8M x 32N).
__global__ __launch_bounds__(512, 1)
void gemm8n_fc1(const u16* A, const u16* Bw, void* Cv) {
  int flat = blockIdx.x;
  int swz = (flat & 7) * 32 + (flat >> 3);
  gemm8n_body<0, 1, 0, 0, 16>(A, 1024, Bw, 1024, nullptr, Cv, 4096,
                              swz & 7, swz >> 3, nullptr);
}
// fc2 split-K=4: K-slice 1024 (KT=16) -> f32 partial P[z]. Grid 256.
__global__ __launch_bounds__(512, 1)
void gemm8n_fc2(const u16* A, const u16* Bw, float* P) {
  int flat = blockIdx.x;
  int swz = (flat & 7) * 32 + (flat >> 3);
  const int bx = swz & 7, by = (swz >> 3) & 7, z = swz >> 6;
  gemm8n_body<1, 0, 0, 0, 16>(A + z * 1024, 4096, Bw + z * 1024, 4096, nullptr,
                              P + (size_t)z * M_ * D_, 1024, bx, by, nullptr);
}

// ---------------------------------------------------------------------------
// 256x256 8-phase GEMM for the logits layer (T2+T3+T4+T5).
// C stores nontemporal (never re-read; keep B-panels L2-resident).
// ---------------------------------------------------------------------------
__global__ __launch_bounds__(512, 2)
void gemm8_logits(const u16* __restrict__ A, const u16* __restrict__ Bw,
                  const float* __restrict__ bias, float* __restrict__ C)
{
  int flat = blockIdx.x;
  int swz = (flat & 7) * 125 + (flat >> 3);
  const int bx = swz & 7;
  const int by = swz >> 3;
  const int m0 = bx << 8, n0 = by << 8;

  __shared__ __align__(16) u16 lds[65536];   // 128 KiB

  const int tid = threadIdx.x, lane = tid & 63, wave = tid >> 6;
  const int wm = wave >> 2, wn = wave & 3;
  const int l15 = lane & 15, l4 = lane >> 4;

  f32x4 acc[8][4];
  const f32x4 z4 = {0.f, 0.f, 0.f, 0.f};
#pragma unroll
  for (int i = 0; i < 8; ++i)
#pragma unroll
    for (int j = 0; j < 4; ++j) acc[i][j] = z4;

  auto stg = [&](const u16* G, int rowbase, int slot, int kt, int kh) {
    kt = (kt < 15) ? kt : 15;
#pragma unroll
    for (int r = 0; r < 2; ++r) {
      const int u = r * 512 + (wave << 6) + lane;
      const int rw = u >> 2, ks = u & 3;
      const int ksw = ks ^ ((rw >> 1) & 3);
      const u16* src = G + (size_t)(rowbase + rw) * 1024 + (kt << 6) + (kh << 5) + (ksw << 3);
      gload16(src, &lds[slot + r * 4096 + (wave << 9)]);
    }
  };

  s16x8 af[4], bfr[4];

#define LDA4(bb, kk, mh)                                                      \
  {                                                                           \
    _Pragma("unroll") for (int f = 0; f < 4; ++f) {                           \
      const int rw = wm * 128 + (mh) * 64 + f * 16 + l15;                     \
      af[f] = *(const s16x8*)&lds[(bb) + (kk) * 8192 + rw * 32 +              \
                                  ((l4 ^ ((rw >> 1) & 3)) << 3)];             \
    }                                                                         \
  }
#define LDB4(bb, kk)                                                          \
  {                                                                           \
    _Pragma("unroll") for (int f = 0; f < 4; ++f) {                           \
      const int rn = wn * 64 + f * 16 + l15;                                  \
      bfr[f] = *(const s16x8*)&lds[(bb) + 16384 + (kk) * 8192 + rn * 32 +     \
                                   ((l4 ^ ((rn >> 1) & 3)) << 3)];            \
    }                                                                         \
  }
#define MFMA16(mh)                                                            \
  {                                                                           \
    __builtin_amdgcn_s_barrier();                                             \
    asm volatile("s_waitcnt lgkmcnt(0)" ::: "memory");                        \
    __builtin_amdgcn_sched_barrier(0);                                        \
    __builtin_amdgcn_s_setprio(1);                                            \
    _Pragma("unroll") for (int f = 0; f < 4; ++f)                             \
      _Pragma("unroll") for (int nf = 0; nf < 4; ++nf)                        \
        acc[(mh) * 4 + f][nf] = __builtin_amdgcn_mfma_f32_16x16x32_bf16(      \
            af[f], bfr[nf], acc[(mh) * 4 + f][nf], 0, 0, 0);                  \
    __builtin_amdgcn_s_setprio(0);                                            \
  }
#define BAR() __builtin_amdgcn_s_barrier()
#define VM4() asm volatile("s_waitcnt vmcnt(4)" ::: "memory")

  stg(A,  m0, 0,             0, 0);
  stg(Bw, n0, 16384,         0, 0);
  stg(A,  m0, 8192,          0, 1);
  stg(Bw, n0, 16384 + 8192,  0, 1);
  stg(A,  m0, 32768,         1, 0);
  stg(Bw, n0, 32768 + 16384, 1, 0);
  VM4();
  BAR();

  for (int i = 0; i < 8; ++i) {
    const int t = 2 * i;
    LDA4(0, 0, 0); LDB4(0, 0);
    stg(A, m0, 32768 + 8192, t + 1, 1);
    MFMA16(0); BAR();
    LDA4(0, 0, 1);
    stg(Bw, n0, 32768 + 24576, t + 1, 1);
    MFMA16(1); BAR();
    LDA4(0, 1, 0); LDB4(0, 1);
    stg(A, m0, 0, t + 2, 0);
    MFMA16(0); BAR();
    LDA4(0, 1, 1);
    stg(Bw, n0, 16384, t + 2, 0);
    MFMA16(1); VM4(); BAR();
    LDA4(32768, 0, 0); LDB4(32768, 0);
    stg(A, m0, 8192, t + 2, 1);
    MFMA16(0); BAR();
    LDA4(32768, 0, 1);
    stg(Bw, n0, 16384 + 8192, t + 2, 1);
    MFMA16(1); BAR();
    LDA4(32768, 1, 0); LDB4(32768, 1);
    stg(A, m0, 32768, t + 3, 0);
    MFMA16(0); BAR();
    LDA4(32768, 1, 1);
    stg(Bw, n0, 32768 + 16384, t + 3, 0);
    MFMA16(1); VM4(); BAR();
  }
#undef LDA4
#undef LDB4
#undef MFMA16
#undef BAR
#undef VM4

  float bv[4];
#pragma unroll
  for (int nf = 0; nf < 4; ++nf) bv[nf] = bias[n0 + wn * 64 + nf * 16 + l15];
#pragma unroll
  for (int mf = 0; mf < 8; ++mf) {
    const int row0 = m0 + wm * 128 + mf * 16 + l4 * 4;
#pragma unroll
    for (int nf = 0; nf < 4; ++nf) {
      const int col = n0 + wn * 64 + nf * 16 + l15;
#pragma unroll
      for (int r = 0; r < 4; ++r)
        nt_store(&C[(size_t)(row0 + r) * V_ + col], acc[mf][nf][r] + bv[nf]);
    }
  }
}

// ---------------------------------------------------------------------------
// Fused causal flash attention, load-balanced. Unchanged from R8/R9.
// ---------------------------------------------------------------------------
__global__ __launch_bounds__(128)
void flash_attn(const u16* __restrict__ qkv, const u16* __restrict__ Vt,
                u16* __restrict__ xo)
{
  int flat = blockIdx.x;
  int swz = (flat & 7) * 64 + (flat >> 3);   // 512 blocks, 8 XCD chunks
  const int qb = 31 - (swz & 31);            // 32-row q-tile, descending work
  const int z  = swz >> 5;                   // b*8 + h
  const int b  = z >> 3, hh = z & 7;

  __shared__ __align__(16) u16 Ks[64 * 128];
  __shared__ __align__(16) u16 Vs[128 * 64];
  __shared__ __align__(16) u16 Ps[32 * 80];

  const int tid = threadIdx.x, lane = tid & 63, w = tid >> 6;  // w in {0,1}
  const int l15 = lane & 15, l4 = lane >> 4;
  const float iscale = 0.08838834764831845f;   // 1/sqrt(128)

  const int qrow = qb * 32 + w * 16 + l15;
  const u16* qptr = qkv + ((size_t)(b * T_) + qrow) * (3 * D_) + hh * HD_;

  s16x8 bQ[4];
#pragma unroll
  for (int ks = 0; ks < 4; ++ks)
    bQ[ks] = *(const s16x8*)(qptr + ks * 32 + l4 * 8);

  f32x4 O[8];
#pragma unroll
  for (int i = 0; i < 8; ++i) O[i] = {0.f, 0.f, 0.f, 0.f};
  float m_run = -1e30f, l_run = 0.f;

  const int ntiles = (qb >> 1) + 1;
  for (int kt = 0; kt < ntiles; ++kt) {
    __syncthreads();
    {
      const int r = tid >> 1, c0 = (tid & 1) << 6;
      const u16* src = qkv + ((size_t)(b * T_) + kt * 64 + r) * (3 * D_) + D_ + hh * HD_ + c0;
#pragma unroll
      for (int u = 0; u < 8; ++u) {
        s16x8 v = *(const s16x8*)(src + u * 8);
        const int dblk = (c0 >> 3) + u;
        *(s16x8*)&Ks[r * 128 + ((dblk ^ (r & 7)) << 3)] = v;
      }
      const int d = tid;
      const u16* vsrc = Vt + ((size_t)z * HD_ + d) * T_ + kt * 64;
#pragma unroll
      for (int u = 0; u < 8; ++u) {
        s16x8 v = *(const s16x8*)(vsrc + u * 8);
        *(s16x8*)&Vs[d * 64 + ((u ^ (d & 7)) << 3)] = v;
      }
    }
    __syncthreads();

    f32x4 st[4];
#pragma unroll
    for (int mf = 0; mf < 4; ++mf) st[mf] = {0.f, 0.f, 0.f, 0.f};
#pragma unroll
    for (int ks = 0; ks < 4; ++ks) {
      s16x8 aK[4];
#pragma unroll
      for (int mf = 0; mf < 4; ++mf) {
        const int r = mf * 16 + l15;
        aK[mf] = *(const s16x8*)&Ks[r * 128 + ((((ks << 2) + l4) ^ (r & 7)) << 3)];
      }
#pragma unroll
      for (int mf = 0; mf < 4; ++mf)
        st[mf] = __builtin_amdgcn_mfma_f32_16x16x32_bf16(aK[mf], bQ[ks], st[mf], 0, 0, 0);
    }

    const bool diag = (kt == ntiles - 1);
    float sv[16];
    float mx = -1e30f;
#pragma unroll
    for (int mf = 0; mf < 4; ++mf)
#pragma unroll
      for (int r = 0; r < 4; ++r) {
        float s = st[mf][r] * iscale;
        if (diag) {
          const int k = kt * 64 + mf * 16 + l4 * 4 + r;
          if (k > qrow) s = -1e30f;
        }
        sv[mf * 4 + r] = s;
        mx = fmaxf(mx, s);
      }
    mx = fmaxf(mx, __shfl_xor(mx, 16));
    mx = fmaxf(mx, __shfl_xor(mx, 32));
    const float m_new = fmaxf(m_run, mx);
    const float sc_old = __expf(m_run - m_new);
    float psum = 0.f;
    u16 pb[16];
#pragma unroll
    for (int j = 0; j < 16; ++j) {
      const float p = __expf(sv[j] - m_new);
      psum += p;
      pb[j] = f2bf(p);
    }
    psum += __shfl_xor(psum, 16);
    psum += __shfl_xor(psum, 32);
    l_run = l_run * sc_old + psum;
    m_run = m_new;

    float scr[4];
#pragma unroll
    for (int r = 0; r < 4; ++r) scr[r] = __shfl(sc_old, l4 * 4 + r);
#pragma unroll
    for (int df = 0; df < 8; ++df)
#pragma unroll
      for (int r = 0; r < 4; ++r) O[df][r] *= scr[r];

    {
      const int row = w * 16 + l15;
#pragma unroll
      for (int j = 0; j < 16; ++j) {
        const int k = (j >> 2) * 16 + l4 * 4 + (j & 3);
        Ps[row * 80 + (((k >> 3) ^ (l15 & 7)) << 3) + (k & 7)] = pb[j];
      }
    }

#pragma unroll
    for (int kc = 0; kc < 2; ++kc) {
      const int prow = w * 16 + l15;
      s16x8 aP = *(const s16x8*)&Ps[prow * 80 + ((((kc << 2) + l4) ^ (l15 & 7)) << 3)];
#pragma unroll
      for (int df = 0; df < 8; ++df) {
        const int d = df * 16 + l15;
        s16x8 bV = *(const s16x8*)&Vs[d * 64 + ((((kc << 2) + l4) ^ (d & 7)) << 3)];
        O[df] = __builtin_amdgcn_mfma_f32_16x16x32_bf16(aP, bV, O[df], 0, 0, 0);
      }
    }
  }

  const float inv_l = 1.0f / l_run;
  float invr[4];
#pragma unroll
  for (int r = 0; r < 4; ++r) invr[r] = __shfl(inv_l, l4 * 4 + r);
#pragma unroll
  for (int df = 0; df < 8; ++df)
#pragma unroll
    for (int r = 0; r < 4; ++r) {
      const int row = qb * 32 + w * 16 + l4 * 4 + r;
      xo[((size_t)(b * T_) + row) * D_ + hh * HD_ + df * 16 + l15] =
          f2bf(O[df][r] * invr[r]);
    }
}

// ---------------------------------------------------------------------------
// Embedding: h[row] = tok_emb[x[row]] + pos_emb[row % T]   (f32 out)
// ---------------------------------------------------------------------------
__global__ __launch_bounds__(256)
void embed_kernel(const int* __restrict__ x, const float* __restrict__ tok,
                  const float* __restrict__ pos, float* __restrict__ h)
{
  const int row = blockIdx.x, tid = threadIdx.x;
  const int t = row & (T_ - 1);
  const int id = x[row];
  f32x4 a = *(const f32x4*)&tok[(size_t)id * D_ + tid * 4];
  f32x4 p = *(const f32x4*)&pos[(size_t)t * D_ + tid * 4];
  f32x4 o = {a[0] + p[0], a[1] + p[1], a[2] + p[2], a[3] + p[3]};
  *(f32x4*)&h[(size_t)row * D_ + tid * 4] = o;
}

// ---------------------------------------------------------------------------
extern "C" void kernel_launch(void* const* d_in, const int* in_sizes, int n_in,
                              void* d_out, int out_size, void* d_ws, size_t ws_size,
                              hipStream_t stream)
{
  (void)in_sizes; (void)n_in; (void)out_size; (void)ws_size;
  const int*   x     = (const int*)  d_in[0];
  const float* tok   = (const float*)d_in[1];
  const float* pos   = (const float*)d_in[2];
  const float* ln1_g = (const float*)d_in[3];
  const float* ln1_b = (const float*)d_in[4];
  const float* wqkv  = (const float*)d_in[5];
  const float* bqkv  = (const float*)d_in[6];
  const float* wo    = (const float*)d_in[7];
  const float* bo    = (const float*)d_in[8];
  const float* ln2_g = (const float*)d_in[9];
  const float* ln2_b = (const float*)d_in[10];
  const float* wfc   = (const float*)d_in[11];
  const float* wfc2  = (const float*)d_in[12];
  const float* fn_g  = (const float*)d_in[13];
  const float* fn_b  = (const float*)d_in[14];
  const float* wout  = (const float*)d_in[15];
  const float* bout  = (const float*)d_in[16];
  float* out = (float*)d_out;

  // ws layout (104.9 MB peak): h f32 | xn | Wq | Wo | Wf1 | Wf2 | qkv | Vt |
  // S(fc1) | P(partials f32, 4 slices). P lifetimes per layer:
  //   conv4ln folds fc2 P[0..3] (layer l-1) -> dead
  //   gemm8n_wo writes P[0..3]; ln_fold4 folds -> dead
  //   gemm8n_fc2 writes P[0..3] (folded next layer / final LN)
  // WoutT (65.5MB) overlays Wq..; overlay end < P start (P read by final LN).
  float* h  = (float*)d_ws;                 // 2048*1024 f32
  u16* xn   = (u16*)(h + (size_t)M_ * D_);  // 2048*1024
  u16* Wq   = xn  + (size_t)M_ * D_;        // 3072*1024
  u16* Wo   = Wq  + (size_t)3 * D_ * D_;    // 1024*1024
  u16* Wf1  = Wo  + (size_t)D_ * D_;        // 4096*1024
  u16* Wf2  = Wf1 + (size_t)4 * D_ * D_;    // 1024*4096
  u16* qkv  = Wf2 + (size_t)4 * D_ * D_;    // 2048*3072 (V third unused)
  u16* Vt   = qkv + (size_t)M_ * 3 * D_;    // 2*1024*1024  [b][hh*128+d][t]
  u16* S    = Vt  + (size_t)2 * T_ * D_;    // fc1 buffer (2048*4096)
  float* P  = (float*)(S + (size_t)M_ * 4 * D_);  // 4*2048*1024 f32
  u16* WoutT = Wq;                          // 32000*1024 overlay

  embed_kernel<<<M_, 256, 0, stream>>>(x, tok, pos, h);

  for (int l = 0; l < L_; ++l) {
    // fused: ln1 (with fc2-partial fold for l>0) + 4 weight transposes
    conv4ln_kernel<<<5120, 256, 0, stream>>>(
        wqkv + (size_t)l * D_ * 3 * D_, wo + (size_t)l * D_ * D_,
        wfc + (size_t)l * D_ * 4 * D_, wfc2 + (size_t)l * 4 * D_ * D_,
        Wq, Wo, Wf1, Wf2,
        h, P, ln1_g + l * D_, ln1_b + l * D_, xn, l > 0 ? 1 : 0);
    // qkv = xn @ WqT + bqkv (8-phase 256x128, 192 blocks); V-cols -> Vt
    gemm8n_qkv<<<192, 512, 0, stream>>>(xn, Wq, bqkv + l * 3 * D_, qkv, Vt);
    // fused causal attention -> xn (bf16); 512 balanced blocks
    flash_attn<<<512, 128, 0, stream>>>(qkv, Vt, xn);
    // attn @ WoT split-K=4 (8-phase KT=4, 256 blocks) -> P[0..3]
    gemm8n_wo<<<256, 512, 0, stream>>>(xn, Wo, P);
    // ln2 with fold: h += P0..P3+bo, then LN -> xn
    ln_fold4<<<M_, 256, 0, stream>>>(h, P, bo + l * D_,
                                     ln2_g + l * D_, ln2_b + l * D_, xn);
    // fc1 = gelu(xn @ Wf1T)   (8-phase 256x128, 256 blocks)
    gemm8n_fc1<<<256, 512, 0, stream>>>(xn, Wf1, S);
    // fc2 split-K=4 -> f32 partials P (folded by next fused LN)
    gemm8n_fc2<<<256, 512, 0, stream>>>(S, Wf2, P);
  }

  // fused: final LN (folds layer-3 partials) + wout transpose; then logits
  convwout_ln<<<10048, 256, 0, stream>>>(wout, WoutT, h, P, fn_g, fn_b, xn);
  gemm8_logits<<<1000, 512, 0, stream>>>(xn, WoutT, bout, out);
}

// Round 11
// 841.614 us; speedup vs baseline: 1.0149x; 1.0149x over previous
//
#include <hip/hip_runtime.h>
#include <math.h>
#include <stdint.h>

#define D_  1024
#define T_  1024
#define H_  8
#define HD_ 128
#define L_  4
#define V_  32000
#define M_  2048   // B*T

typedef __attribute__((ext_vector_type(4))) float f32x4;
typedef __attribute__((ext_vector_type(4))) short s16x4;
typedef __attribute__((ext_vector_type(8))) short s16x8;
typedef unsigned short u16;

__device__ __forceinline__ u16 f2bf(float f) {
  union { float f; uint32_t u; } c; c.f = f;
  uint32_t r = c.u + 0x7fffu + ((c.u >> 16) & 1u);   // RTN-even
  return (u16)(r >> 16);
}
__device__ __forceinline__ float bf2f(u16 h) {
  union { uint32_t u; float f; } c; c.u = ((uint32_t)h) << 16;
  return c.f;
}
__device__ __forceinline__ float gelu_f(float x) {
  return 0.5f * x * (1.0f + erff(x * 0.70710678118654752f));
}

// async global->LDS, 16B per lane. LDS dest is wave-uniform base (HW adds
// lane*16); global ptr is per-lane. [guide §5, m97/m104]
__device__ __forceinline__ void gload16(const u16* g, u16* l) {
  __builtin_amdgcn_global_load_lds(
      (const __attribute__((address_space(1))) void*)(uintptr_t)g,
      (__attribute__((address_space(3))) void*)(uint32_t)(uintptr_t)l,
      16, 0, 0);
}

// ---------------------------------------------------------------------------
// Transpose-convert body: in f32 [R][C] -> out bf16 [C][R], one 64x64 tile.
// ---------------------------------------------------------------------------
__device__ __forceinline__ void convT_f32_tile(const float* __restrict__ in,
                                               u16* __restrict__ out,
                                               int ldin, int ldout,
                                               int c0, int r0,
                                               u16 (*tile)[72])
{
  const int t = threadIdx.x;
  const int rr = t >> 2, cs = (t & 3) << 4;
  u16 tmp[16];
  const float* p = in + (size_t)(r0 + rr) * ldin + c0 + cs;
#pragma unroll
  for (int q = 0; q < 4; ++q) {
    f32x4 v = *(const f32x4*)(p + q * 4);
#pragma unroll
    for (int j = 0; j < 4; ++j) tmp[q * 4 + j] = f2bf(v[j]);
  }
  *(s16x8*)&tile[rr][cs]     = *(const s16x8*)tmp;
  *(s16x8*)&tile[rr][cs + 8] = *(const s16x8*)(tmp + 8);
  __syncthreads();
  const int cr = t >> 2, rs = (t & 3) << 4;
  u16 o[16];
#pragma unroll
  for (int j = 0; j < 16; ++j) o[j] = tile[rs + j][cr];
  u16* op = out + (size_t)(c0 + cr) * ldout + r0 + rs;
  *(s16x8*)op       = *(const s16x8*)o;
  *(s16x8*)(op + 8) = *(const s16x8*)(o + 8);
}

// ---------------------------------------------------------------------------
// LayerNorm row body (+optional 4-way fc2-partial fold).
// ---------------------------------------------------------------------------
__device__ __forceinline__
void ln_row_body(int row, float* __restrict__ hbuf, const float* __restrict__ P,
                 const float* __restrict__ g, const float* __restrict__ b,
                 u16* __restrict__ y, int red, float* red_s)
{
  const int tid = threadIdx.x;
  const size_t i = (size_t)row * D_ + tid * 4;
  f32x4 v = *(const f32x4*)&hbuf[i];
  if (red) {
#pragma unroll
    for (int zp = 0; zp < 4; ++zp) {
      f32x4 p = *(const f32x4*)&P[(size_t)zp * M_ * D_ + i];
      v[0] += p[0]; v[1] += p[1]; v[2] += p[2]; v[3] += p[3];
    }
    *(f32x4*)&hbuf[i] = v;
  }
  float s  = v[0] + v[1] + v[2] + v[3];
  float s2 = v[0]*v[0] + v[1]*v[1] + v[2]*v[2] + v[3]*v[3];
#pragma unroll
  for (int off = 32; off > 0; off >>= 1) {
    s  += __shfl_xor(s, off);
    s2 += __shfl_xor(s2, off);
  }
  if ((tid & 63) == 0) { red_s[tid >> 6] = s; red_s[4 + (tid >> 6)] = s2; }
  __syncthreads();
  s  = red_s[0] + red_s[1] + red_s[2] + red_s[3];
  s2 = red_s[4] + red_s[5] + red_s[6] + red_s[7];
  const float mean = s * (1.0f / D_);
  const float var  = s2 * (1.0f / D_) - mean * mean;
  const float rs   = rsqrtf(var + 1e-5f);
  f32x4 gg = *(const f32x4*)&g[tid * 4];
  f32x4 bb = *(const f32x4*)&b[tid * 4];
  u16 o[4];
#pragma unroll
  for (int j = 0; j < 4; ++j) o[j] = f2bf((v[j] - mean) * rs * gg[j] + bb[j]);
  *(s16x4*)&y[i] = *(const s16x4*)o;
}

// Fused: ln1 (rows 0..2047, optional fc2-partial fold) + 4 weight transposes.
__global__ __launch_bounds__(256)
void conv4ln_kernel(const float* __restrict__ wqkv_l, const float* __restrict__ wo_l,
                    const float* __restrict__ wfc_l, const float* __restrict__ wfc2_l,
                    u16* __restrict__ Wq, u16* __restrict__ Wo,
                    u16* __restrict__ Wf1, u16* __restrict__ Wf2,
                    float* __restrict__ hbuf, const float* __restrict__ P,
                    const float* __restrict__ g, const float* __restrict__ b,
                    u16* __restrict__ y, int red)
{
  __shared__ __align__(16) u16 tile[64][72];
  int f = blockIdx.x;
  if (f < 2048) { ln_row_body(f, hbuf, P, g, b, y, red, (float*)tile); return; }
  f -= 2048;
  if (f < 768) {
    convT_f32_tile(wqkv_l, Wq, 3 * D_, D_, (f % 48) << 6, (f / 48) << 6, tile);
  } else if (f < 1024) {
    f -= 768;
    convT_f32_tile(wo_l, Wo, D_, D_, (f & 15) << 6, (f >> 4) << 6, tile);
  } else if (f < 2048) {
    f -= 1024;
    convT_f32_tile(wfc_l, Wf1, 4 * D_, D_, (f & 63) << 6, (f >> 6) << 6, tile);
  } else {
    f -= 2048;
    convT_f32_tile(wfc2_l, Wf2, D_, 4 * D_, (f & 15) << 6, (f >> 4) << 6, tile);
  }
}

// Fused: final LN (folds fc2 partials) + wout transpose (blocks 2048..10047).
__global__ __launch_bounds__(256)
void convwout_ln(const float* __restrict__ wout, u16* __restrict__ WoutT,
                 float* __restrict__ hbuf, const float* __restrict__ P,
                 const float* __restrict__ g, const float* __restrict__ b,
                 u16* __restrict__ y)
{
  __shared__ __align__(16) u16 tile[64][72];
  int f = blockIdx.x;
  if (f < 2048) { ln_row_body(f, hbuf, P, g, b, y, 1, (float*)tile); return; }
  f -= 2048;
  convT_f32_tile(wout, WoutT, V_, D_, (f % 500) << 6, (f / 500) << 6, tile);
}

// ln2 with 4-way wo-partial fold + bo: h += P0+P1+P2+P3+bo, then LN -> y.
__global__ __launch_bounds__(256)
void ln_fold4(float* __restrict__ hbuf, const float* __restrict__ P,
              const float* __restrict__ bo, const float* __restrict__ g,
              const float* __restrict__ b, u16* __restrict__ y)
{
  __shared__ float red_s[8];
  const int row = blockIdx.x, tid = threadIdx.x;
  const size_t i = (size_t)row * D_ + tid * 4;
  f32x4 v = *(const f32x4*)&hbuf[i];
  f32x4 bb4 = *(const f32x4*)&bo[tid * 4];
#pragma unroll
  for (int zp = 0; zp < 4; ++zp) {
    f32x4 p = *(const f32x4*)&P[(size_t)zp * M_ * D_ + i];
    v[0] += p[0]; v[1] += p[1]; v[2] += p[2]; v[3] += p[3];
  }
#pragma unroll
  for (int j = 0; j < 4; ++j) v[j] += bb4[j];
  *(f32x4*)&hbuf[i] = v;
  float s  = v[0] + v[1] + v[2] + v[3];
  float s2 = v[0]*v[0] + v[1]*v[1] + v[2]*v[2] + v[3]*v[3];
#pragma unroll
  for (int off = 32; off > 0; off >>= 1) {
    s  += __shfl_xor(s, off);
    s2 += __shfl_xor(s2, off);
  }
  if ((tid & 63) == 0) { red_s[tid >> 6] = s; red_s[4 + (tid >> 6)] = s2; }
  __syncthreads();
  s  = red_s[0] + red_s[1] + red_s[2] + red_s[3];
  s2 = red_s[4] + red_s[5] + red_s[6] + red_s[7];
  const float mean = s * (1.0f / D_);
  const float var  = s2 * (1.0f / D_) - mean * mean;
  const float rs   = rsqrtf(var + 1e-5f);
  f32x4 gg = *(const f32x4*)&g[tid * 4];
  f32x4 bbn = *(const f32x4*)&b[tid * 4];
  u16 o[4];
#pragma unroll
  for (int j = 0; j < 4; ++j) o[j] = f2bf((v[j] - mean) * rs * gg[j] + bbn[j]);
  *(s16x4*)&y[i] = *(const s16x4*)o;
}

// ---------------------------------------------------------------------------
// 256x128-tile 8-phase GEMM (gemm8n), KT parameterized (K = KT*64).
// Ledger (3 gloads/phase/wave): prologue stages t0{kh0,kh1}+t1{kh0} (9 loads),
// VM6 lands t0.kh0. Each phase stages one half-set 3-ahead; VM6 retires
// exactly the half-set the next phase reads. Tail: kt clamped to KT-1
// (redundant re-stage into WAR-safe dead slots keeps counts uniform).
// Verified by simulation for KT=16 (R7) and KT=4 (R10).
// VSPLIT: blocks with n0>=2048 write transposed to VtOut[b][col-2048][t].
// OUT: 0 bf16, 1 f32. BIAS adds bias[col]. ACT = gelu.
// ---------------------------------------------------------------------------
template<int OUT, int ACT, int BIAS, int VSPLIT, int KT>
__device__ __forceinline__
void gemm8n_body(const u16* __restrict__ A, int lda,
                 const u16* __restrict__ Bw, int ldb,
                 const float* __restrict__ bias,
                 void* __restrict__ Cv, int ldc, int bx, int by,
                 u16* __restrict__ VtOut)
{
  const int m0 = bx << 8, n0 = by << 7;

  __shared__ __align__(16) u16 lds[49152];   // 96 KiB

  const int tid = threadIdx.x, lane = tid & 63, wave = tid >> 6;
  const int wm = wave >> 1, wn = wave & 1;
  const int l15 = lane & 15, l4 = lane >> 4;

  f32x4 acc[4][4];
  const f32x4 z4 = {0.f, 0.f, 0.f, 0.f};
#pragma unroll
  for (int i = 0; i < 4; ++i)
#pragma unroll
    for (int j = 0; j < 4; ++j) acc[i][j] = z4;

  // buf b at b*24576 (u16): A0 +0, A1 +8192, B0 +16384, B1 +20480
  auto stgA = [&](int buf, int kt, int kh) {
    kt = (kt < KT - 1) ? kt : (KT - 1);
    const int slot = buf * 24576 + kh * 8192;
#pragma unroll
    for (int r = 0; r < 2; ++r) {
      const int u = r * 512 + (wave << 6) + lane;
      const int rw = u >> 2, ks = u & 3;
      const int ksw = ks ^ ((rw >> 1) & 3);
      gload16(A + (size_t)(m0 + rw) * lda + (kt << 6) + (kh << 5) + (ksw << 3),
              &lds[slot + r * 4096 + (wave << 9)]);
    }
  };
  auto stgB = [&](int buf, int kt, int kh) {
    kt = (kt < KT - 1) ? kt : (KT - 1);
    const int slot = buf * 24576 + 16384 + kh * 4096;
    const int u = (wave << 6) + lane;
    const int rw = u >> 2, ks = u & 3;
    const int ksw = ks ^ ((rw >> 1) & 3);
    gload16(Bw + (size_t)(n0 + rw) * ldb + (kt << 6) + (kh << 5) + (ksw << 3),
            &lds[slot + (wave << 9)]);
  };

  s16x8 af[4], bfr[4];

#define LDABN(bb, kk)                                                         \
  {                                                                           \
    _Pragma("unroll") for (int f = 0; f < 4; ++f) {                           \
      const int rw = wm * 64 + f * 16 + l15;                                  \
      af[f] = *(const s16x8*)&lds[(bb) + (kk) * 8192 + rw * 32 +              \
                                  ((l4 ^ ((rw >> 1) & 3)) << 3)];             \
    }                                                                         \
    _Pragma("unroll") for (int f = 0; f < 4; ++f) {                           \
      const int rn = wn * 64 + f * 16 + l15;                                  \
      bfr[f] = *(const s16x8*)&lds[(bb) + 16384 + (kk) * 4096 + rn * 32 +     \
                                   ((l4 ^ ((rn >> 1) & 3)) << 3)];            \
    }                                                                         \
  }
#define MFMAN()                                                               \
  {                                                                           \
    __builtin_amdgcn_s_barrier();                                             \
    asm volatile("s_waitcnt lgkmcnt(0)" ::: "memory");                        \
    __builtin_amdgcn_sched_barrier(0);                                        \
    __builtin_amdgcn_s_setprio(1);                                            \
    _Pragma("unroll") for (int f = 0; f < 4; ++f)                             \
      _Pragma("unroll") for (int nf = 0; nf < 4; ++nf)                        \
        acc[f][nf] = __builtin_amdgcn_mfma_f32_16x16x32_bf16(                 \
            af[f], bfr[nf], acc[f][nf], 0, 0, 0);                             \
    __builtin_amdgcn_s_setprio(0);                                            \
  }
#define BARN() __builtin_amdgcn_s_barrier()
#define VM6()  asm volatile("s_waitcnt vmcnt(6)" ::: "memory")

  stgA(0, 0, 0); stgB(0, 0, 0);
  stgA(0, 0, 1); stgB(0, 0, 1);
  stgA(1, 1, 0); stgB(1, 1, 0);
  VM6();
  BARN();

  for (int i = 0; i < KT / 2; ++i) {
    const int t = 2 * i;
    LDABN(0, 0);
    stgA(1, t + 1, 1); stgB(1, t + 1, 1);
    MFMAN(); VM6(); BARN();
    LDABN(0, 1);
    stgA(0, t + 2, 0); stgB(0, t + 2, 0);
    MFMAN(); VM6(); BARN();
    LDABN(24576, 0);
    stgA(0, t + 2, 1); stgB(0, t + 2, 1);
    MFMAN(); VM6(); BARN();
    LDABN(24576, 1);
    stgA(1, t + 3, 0); stgB(1, t + 3, 0);
    MFMAN(); VM6(); BARN();
  }
#undef LDABN
#undef MFMAN
#undef BARN
#undef VM6

  // epilogue: col = l15, row = l4*4 + r per 16x16 fragment [m89]
  if (VSPLIT && n0 >= 2048) {
    // V-direct transpose: rows row0..+3 -> consecutive t in Vt[b][d][t]
#pragma unroll
    for (int mf = 0; mf < 4; ++mf) {
      const int row0 = m0 + wm * 64 + mf * 16 + l4 * 4;
      const int bb = row0 >> 10, t0 = row0 & 1023;
#pragma unroll
      for (int nf = 0; nf < 4; ++nf) {
        const int col = n0 + wn * 64 + nf * 16 + l15;
        const float bv = BIAS ? bias[col] : 0.0f;
        u16 o4[4];
#pragma unroll
        for (int r = 0; r < 4; ++r) o4[r] = f2bf(acc[mf][nf][r] + bv);
        *(s16x4*)&VtOut[((size_t)(bb << 10) + (col - 2048)) * 1024 + t0] =
            *(const s16x4*)o4;
      }
    }
    return;
  }
  float* Cf = (float*)Cv;
  u16*   Ch = (u16*)Cv;
#pragma unroll
  for (int mf = 0; mf < 4; ++mf) {
    const int row0 = m0 + wm * 64 + mf * 16 + l4 * 4;
#pragma unroll
    for (int nf = 0; nf < 4; ++nf) {
      const int col = n0 + wn * 64 + nf * 16 + l15;
      const float bv = BIAS ? bias[col] : 0.0f;
#pragma unroll
      for (int r = 0; r < 4; ++r) {
        float v = acc[mf][nf][r] + bv;
        if (ACT) v = gelu_f(v);
        const size_t idx = (size_t)(row0 + r) * ldc + col;
        if (OUT == 0) Ch[idx] = f2bf(v);
        else          Cf[idx] = v;
      }
    }
  }
}

// qkv: M=2048 x N=3072 x K=1024; grid 192 (8M x 24N); V-cols -> Vt direct.
__global__ __launch_bounds__(512, 1)
void gemm8n_qkv(const u16* A, const u16* Bw, const float* bias, u16* C, u16* Vt) {
  int flat = blockIdx.x;
  int swz = (flat & 7) * 24 + (flat >> 3);
  gemm8n_body<0, 0, 1, 1, 16>(A, 1024, Bw, 1024, bias, C, 3 * D_,
                              swz & 7, swz >> 3, Vt);
}
// wo split-K=4: K-slice 256 (KT=4) -> f32 partial P[z]. Grid 256 (8x8x4).
__global__ __launch_bounds__(512, 1)
void gemm8n_wo(const u16* A, const u16* Bw, float* P) {
  int flat = blockIdx.x;
  int swz = (flat & 7) * 32 + (flat >> 3);
  const int bx = swz & 7, by = (swz >> 3) & 7, z = swz >> 6;
  gemm8n_body<1, 0, 0, 0, 4>(A + z * 256, 1024, Bw + z * 256, 1024, nullptr,
                             P + (size_t)z * M_ * D_, 1024, bx, by, nullptr);
}
// fc1: gelu(xn @ Wf1T) -> bf16 S. Grid 256 (8M x 32N).
__global__ __launch_bounds__(512, 1)
void gemm8n_fc1(const u16* A, const u16* Bw, void* Cv) {
  int flat = blockIdx.x;
  int swz = (flat & 7) * 32 + (flat >> 3);
  gemm8n_body<0, 1, 0, 0, 16>(A, 1024, Bw, 1024, nullptr, Cv, 4096,
                              swz & 7, swz >> 3, nullptr);
}
// fc2 split-K=4: K-slice 1024 (KT=16) -> f32 partial P[z]. Grid 256.
__global__ __launch_bounds__(512, 1)
void gemm8n_fc2(const u16* A, const u16* Bw, float* P) {
  int flat = blockIdx.x;
  int swz = (flat & 7) * 32 + (flat >> 3);
  const int bx = swz & 7, by = (swz >> 3) & 7, z = swz >> 6;
  gemm8n_body<1, 0, 0, 0, 16>(A + z * 1024, 4096, Bw + z * 1024, 4096, nullptr,
                              P + (size_t)z * M_ * D_, 1024, bx, by, nullptr);
}

// ---------------------------------------------------------------------------
// 256x256 8-phase GEMM for the logits layer (T2+T3+T4+T5). Plain C stores
// (R10 post-mortem: nontemporal stores caused +43MB write amplification).
// ---------------------------------------------------------------------------
__global__ __launch_bounds__(512, 2)
void gemm8_logits(const u16* __restrict__ A, const u16* __restrict__ Bw,
                  const float* __restrict__ bias, float* __restrict__ C)
{
  int flat = blockIdx.x;
  int swz = (flat & 7) * 125 + (flat >> 3);
  const int bx = swz & 7;
  const int by = swz >> 3;
  const int m0 = bx << 8, n0 = by << 8;

  __shared__ __align__(16) u16 lds[65536];   // 128 KiB

  const int tid = threadIdx.x, lane = tid & 63, wave = tid >> 6;
  const int wm = wave >> 2, wn = wave & 3;
  const int l15 = lane & 15, l4 = lane >> 4;

  f32x4 acc[8][4];
  const f32x4 z4 = {0.f, 0.f, 0.f, 0.f};
#pragma unroll
  for (int i = 0; i < 8; ++i)
#pragma unroll
    for (int j = 0; j < 4; ++j) acc[i][j] = z4;

  auto stg = [&](const u16* G, int rowbase, int slot, int kt, int kh) {
    kt = (kt < 15) ? kt : 15;
#pragma unroll
    for (int r = 0; r < 2; ++r) {
      const int u = r * 512 + (wave << 6) + lane;
      const int rw = u >> 2, ks = u & 3;
      const int ksw = ks ^ ((rw >> 1) & 3);
      const u16* src = G + (size_t)(rowbase + rw) * 1024 + (kt << 6) + (kh << 5) + (ksw << 3);
      gload16(src, &lds[slot + r * 4096 + (wave << 9)]);
    }
  };

  s16x8 af[4], bfr[4];

#define LDA4(bb, kk, mh)                                                      \
  {                                                                           \
    _Pragma("unroll") for (int f = 0; f < 4; ++f) {                           \
      const int rw = wm * 128 + (mh) * 64 + f * 16 + l15;                     \
      af[f] = *(const s16x8*)&lds[(bb) + (kk) * 8192 + rw * 32 +              \
                                  ((l4 ^ ((rw >> 1) & 3)) << 3)];             \
    }                                                                         \
  }
#define LDB4(bb, kk)                                                          \
  {                                                                           \
    _Pragma("unroll") for (int f = 0; f < 4; ++f) {                           \
      const int rn = wn * 64 + f * 16 + l15;                                  \
      bfr[f] = *(const s16x8*)&lds[(bb) + 16384 + (kk) * 8192 + rn * 32 +     \
                                   ((l4 ^ ((rn >> 1) & 3)) << 3)];            \
    }                                                                         \
  }
#define MFMA16(mh)                                                            \
  {                                                                           \
    __builtin_amdgcn_s_barrier();                                             \
    asm volatile("s_waitcnt lgkmcnt(0)" ::: "memory");                        \
    __builtin_amdgcn_sched_barrier(0);                                        \
    __builtin_amdgcn_s_setprio(1);                                            \
    _Pragma("unroll") for (int f = 0; f < 4; ++f)                             \
      _Pragma("unroll") for (int nf = 0; nf < 4; ++nf)                        \
        acc[(mh) * 4 + f][nf] = __builtin_amdgcn_mfma_f32_16x16x32_bf16(      \
            af[f], bfr[nf], acc[(mh) * 4 + f][nf], 0, 0, 0);                  \
    __builtin_amdgcn_s_setprio(0);                                            \
  }
#define BAR() __builtin_amdgcn_s_barrier()
#define VM4() asm volatile("s_waitcnt vmcnt(4)" ::: "memory")

  stg(A,  m0, 0,             0, 0);
  stg(Bw, n0, 16384,         0, 0);
  stg(A,  m0, 8192,          0, 1);
  stg(Bw, n0, 16384 + 8192,  0, 1);
  stg(A,  m0, 32768,         1, 0);
  stg(Bw, n0, 32768 + 16384, 1, 0);
  VM4();
  BAR();

  for (int i = 0; i < 8; ++i) {
    const int t = 2 * i;
    LDA4(0, 0, 0); LDB4(0, 0);
    stg(A, m0, 32768 + 8192, t + 1, 1);
    MFMA16(0); BAR();
    LDA4(0, 0, 1);
    stg(Bw, n0, 32768 + 24576, t + 1, 1);
    MFMA16(1); BAR();
    LDA4(0, 1, 0); LDB4(0, 1);
    stg(A, m0, 0, t + 2, 0);
    MFMA16(0); BAR();
    LDA4(0, 1, 1);
    stg(Bw, n0, 16384, t + 2, 0);
    MFMA16(1); VM4(); BAR();
    LDA4(32768, 0, 0); LDB4(32768, 0);
    stg(A, m0, 8192, t + 2, 1);
    MFMA16(0); BAR();
    LDA4(32768, 0, 1);
    stg(Bw, n0, 16384 + 8192, t + 2, 1);
    MFMA16(1); BAR();
    LDA4(32768, 1, 0); LDB4(32768, 1);
    stg(A, m0, 32768, t + 3, 0);
    MFMA16(0); BAR();
    LDA4(32768, 1, 1);
    stg(Bw, n0, 32768 + 16384, t + 3, 0);
    MFMA16(1); VM4(); BAR();
  }
#undef LDA4
#undef LDB4
#undef MFMA16
#undef BAR
#undef VM4

  float bv[4];
#pragma unroll
  for (int nf = 0; nf < 4; ++nf) bv[nf] = bias[n0 + wn * 64 + nf * 16 + l15];
#pragma unroll
  for (int mf = 0; mf < 8; ++mf) {
    const int row0 = m0 + wm * 128 + mf * 16 + l4 * 4;
#pragma unroll
    for (int nf = 0; nf < 4; ++nf) {
      const int col = n0 + wn * 64 + nf * 16 + l15;
#pragma unroll
      for (int r = 0; r < 4; ++r)
        C[(size_t)(row0 + r) * V_ + col] = acc[mf][nf][r] + bv[nf];
    }
  }
}

// ---------------------------------------------------------------------------
// Fused causal flash attention, load-balanced. Unchanged from R8/R9.
// ---------------------------------------------------------------------------
__global__ __launch_bounds__(128)
void flash_attn(const u16* __restrict__ qkv, const u16* __restrict__ Vt,
                u16* __restrict__ xo)
{
  int flat = blockIdx.x;
  int swz = (flat & 7) * 64 + (flat >> 3);   // 512 blocks, 8 XCD chunks
  const int qb = 31 - (swz & 31);            // 32-row q-tile, descending work
  const int z  = swz >> 5;                   // b*8 + h
  const int b  = z >> 3, hh = z & 7;

  __shared__ __align__(16) u16 Ks[64 * 128];
  __shared__ __align__(16) u16 Vs[128 * 64];
  __shared__ __align__(16) u16 Ps[32 * 80];

  const int tid = threadIdx.x, lane = tid & 63, w = tid >> 6;  // w in {0,1}
  const int l15 = lane & 15, l4 = lane >> 4;
  const float iscale = 0.08838834764831845f;   // 1/sqrt(128)

  const int qrow = qb * 32 + w * 16 + l15;
  const u16* qptr = qkv + ((size_t)(b * T_) + qrow) * (3 * D_) + hh * HD_;

  s16x8 bQ[4];
#pragma unroll
  for (int ks = 0; ks < 4; ++ks)
    bQ[ks] = *(const s16x8*)(qptr + ks * 32 + l4 * 8);

  f32x4 O[8];
#pragma unroll
  for (int i = 0; i < 8; ++i) O[i] = {0.f, 0.f, 0.f, 0.f};
  float m_run = -1e30f, l_run = 0.f;

  const int ntiles = (qb >> 1) + 1;
  for (int kt = 0; kt < ntiles; ++kt) {
    __syncthreads();
    {
      const int r = tid >> 1, c0 = (tid & 1) << 6;
      const u16* src = qkv + ((size_t)(b * T_) + kt * 64 + r) * (3 * D_) + D_ + hh * HD_ + c0;
#pragma unroll
      for (int u = 0; u < 8; ++u) {
        s16x8 v = *(const s16x8*)(src + u * 8);
        const int dblk = (c0 >> 3) + u;
        *(s16x8*)&Ks[r * 128 + ((dblk ^ (r & 7)) << 3)] = v;
      }
      const int d = tid;
      const u16* vsrc = Vt + ((size_t)z * HD_ + d) * T_ + kt * 64;
#pragma unroll
      for (int u = 0; u < 8; ++u) {
        s16x8 v = *(const s16x8*)(vsrc + u * 8);
        *(s16x8*)&Vs[d * 64 + ((u ^ (d & 7)) << 3)] = v;
      }
    }
    __syncthreads();

    f32x4 st[4];
#pragma unroll
    for (int mf = 0; mf < 4; ++mf) st[mf] = {0.f, 0.f, 0.f, 0.f};
#pragma unroll
    for (int ks = 0; ks < 4; ++ks) {
      s16x8 aK[4];
#pragma unroll
      for (int mf = 0; mf < 4; ++mf) {
        const int r = mf * 16 + l15;
        aK[mf] = *(const s16x8*)&Ks[r * 128 + ((((ks << 2) + l4) ^ (r & 7)) << 3)];
      }
#pragma unroll
      for (int mf = 0; mf < 4; ++mf)
        st[mf] = __builtin_amdgcn_mfma_f32_16x16x32_bf16(aK[mf], bQ[ks], st[mf], 0, 0, 0);
    }

    const bool diag = (kt == ntiles - 1);
    float sv[16];
    float mx = -1e30f;
#pragma unroll
    for (int mf = 0; mf < 4; ++mf)
#pragma unroll
      for (int r = 0; r < 4; ++r) {
        float s = st[mf][r] * iscale;
        if (diag) {
          const int k = kt * 64 + mf * 16 + l4 * 4 + r;
          if (k > qrow) s = -1e30f;
        }
        sv[mf * 4 + r] = s;
        mx = fmaxf(mx, s);
      }
    mx = fmaxf(mx, __shfl_xor(mx, 16));
    mx = fmaxf(mx, __shfl_xor(mx, 32));
    const float m_new = fmaxf(m_run, mx);
    const float sc_old = __expf(m_run - m_new);
    float psum = 0.f;
    u16 pb[16];
#pragma unroll
    for (int j = 0; j < 16; ++j) {
      const float p = __expf(sv[j] - m_new);
      psum += p;
      pb[j] = f2bf(p);
    }
    psum += __shfl_xor(psum, 16);
    psum += __shfl_xor(psum, 32);
    l_run = l_run * sc_old + psum;
    m_run = m_new;

    float scr[4];
#pragma unroll
    for (int r = 0; r < 4; ++r) scr[r] = __shfl(sc_old, l4 * 4 + r);
#pragma unroll
    for (int df = 0; df < 8; ++df)
#pragma unroll
      for (int r = 0; r < 4; ++r) O[df][r] *= scr[r];

    {
      const int row = w * 16 + l15;
#pragma unroll
      for (int j = 0; j < 16; ++j) {
        const int k = (j >> 2) * 16 + l4 * 4 + (j & 3);
        Ps[row * 80 + (((k >> 3) ^ (l15 & 7)) << 3) + (k & 7)] = pb[j];
      }
    }

#pragma unroll
    for (int kc = 0; kc < 2; ++kc) {
      const int prow = w * 16 + l15;
      s16x8 aP = *(const s16x8*)&Ps[prow * 80 + ((((kc << 2) + l4) ^ (l15 & 7)) << 3)];
#pragma unroll
      for (int df = 0; df < 8; ++df) {
        const int d = df * 16 + l15;
        s16x8 bV = *(const s16x8*)&Vs[d * 64 + ((((kc << 2) + l4) ^ (d & 7)) << 3)];
        O[df] = __builtin_amdgcn_mfma_f32_16x16x32_bf16(aP, bV, O[df], 0, 0, 0);
      }
    }
  }

  const float inv_l = 1.0f / l_run;
  float invr[4];
#pragma unroll
  for (int r = 0; r < 4; ++r) invr[r] = __shfl(inv_l, l4 * 4 + r);
#pragma unroll
  for (int df = 0; df < 8; ++df)
#pragma unroll
    for (int r = 0; r < 4; ++r) {
      const int row = qb * 32 + w * 16 + l4 * 4 + r;
      xo[((size_t)(b * T_) + row) * D_ + hh * HD_ + df * 16 + l15] =
          f2bf(O[df][r] * invr[r]);
    }
}

// ---------------------------------------------------------------------------
// Embedding: h[row] = tok_emb[x[row]] + pos_emb[row % T]   (f32 out)
// ---------------------------------------------------------------------------
__global__ __launch_bounds__(256)
void embed_kernel(const int* __restrict__ x, const float* __restrict__ tok,
                  const float* __restrict__ pos, float* __restrict__ h)
{
  const int row = blockIdx.x, tid = threadIdx.x;
  const int t = row & (T_ - 1);
  const int id = x[row];
  f32x4 a = *(const f32x4*)&tok[(size_t)id * D_ + tid * 4];
  f32x4 p = *(const f32x4*)&pos[(size_t)t * D_ + tid * 4];
  f32x4 o = {a[0] + p[0], a[1] + p[1], a[2] + p[2], a[3] + p[3]};
  *(f32x4*)&h[(size_t)row * D_ + tid * 4] = o;
}

// ---------------------------------------------------------------------------
extern "C" void kernel_launch(void* const* d_in, const int* in_sizes, int n_in,
                              void* d_out, int out_size, void* d_ws, size_t ws_size,
                              hipStream_t stream)
{
  (void)in_sizes; (void)n_in; (void)out_size; (void)ws_size;
  const int*   x     = (const int*)  d_in[0];
  const float* tok   = (const float*)d_in[1];
  const float* pos   = (const float*)d_in[2];
  const float* ln1_g = (const float*)d_in[3];
  const float* ln1_b = (const float*)d_in[4];
  const float* wqkv  = (const float*)d_in[5];
  const float* bqkv  = (const float*)d_in[6];
  const float* wo    = (const float*)d_in[7];
  const float* bo    = (const float*)d_in[8];
  const float* ln2_g = (const float*)d_in[9];
  const float* ln2_b = (const float*)d_in[10];
  const float* wfc   = (const float*)d_in[11];
  const float* wfc2  = (const float*)d_in[12];
  const float* fn_g  = (const float*)d_in[13];
  const float* fn_b  = (const float*)d_in[14];
  const float* wout  = (const float*)d_in[15];
  const float* bout  = (const float*)d_in[16];
  float* out = (float*)d_out;

  // ws layout (104.9 MB peak): h f32 | xn | Wq | Wo | Wf1 | Wf2 | qkv | Vt |
  // S(fc1) | P(partials f32, 4 slices). P lifetimes per layer:
  //   conv4ln folds fc2 P[0..3] (layer l-1) -> dead
  //   gemm8n_wo writes P[0..3]; ln_fold4 folds -> dead
  //   gemm8n_fc2 writes P[0..3] (folded next layer / final LN)
  // WoutT (65.5MB) overlays Wq..; overlay end < P start (P read by final LN).
  float* h  = (float*)d_ws;                 // 2048*1024 f32
  u16* xn   = (u16*)(h + (size_t)M_ * D_);  // 2048*1024
  u16* Wq   = xn  + (size_t)M_ * D_;        // 3072*1024
  u16* Wo   = Wq  + (size_t)3 * D_ * D_;    // 1024*1024
  u16* Wf1  = Wo  + (size_t)D_ * D_;        // 4096*1024
  u16* Wf2  = Wf1 + (size_t)4 * D_ * D_;    // 1024*4096
  u16* qkv  = Wf2 + (size_t)4 * D_ * D_;    // 2048*3072 (V third unused)
  u16* Vt   = qkv + (size_t)M_ * 3 * D_;    // 2*1024*1024  [b][hh*128+d][t]
  u16* S    = Vt  + (size_t)2 * T_ * D_;    // fc1 buffer (2048*4096)
  float* P  = (float*)(S + (size_t)M_ * 4 * D_);  // 4*2048*1024 f32
  u16* WoutT = Wq;                          // 32000*1024 overlay

  embed_kernel<<<M_, 256, 0, stream>>>(x, tok, pos, h);

  for (int l = 0; l < L_; ++l) {
    // fused: ln1 (with fc2-partial fold for l>0) + 4 weight transposes
    conv4ln_kernel<<<5120, 256, 0, stream>>>(
        wqkv + (size_t)l * D_ * 3 * D_, wo + (size_t)l * D_ * D_,
        wfc + (size_t)l * D_ * 4 * D_, wfc2 + (size_t)l * 4 * D_ * D_,
        Wq, Wo, Wf1, Wf2,
        h, P, ln1_g + l * D_, ln1_b + l * D_, xn, l > 0 ? 1 : 0);
    // qkv = xn @ WqT + bqkv (8-phase 256x128, 192 blocks); V-cols -> Vt
    gemm8n_qkv<<<192, 512, 0, stream>>>(xn, Wq, bqkv + l * 3 * D_, qkv, Vt);
    // fused causal attention -> xn (bf16); 512 balanced blocks
    flash_attn<<<512, 128, 0, stream>>>(qkv, Vt, xn);
    // attn @ WoT split-K=4 (8-phase KT=4, 256 blocks) -> P[0..3]
    gemm8n_wo<<<256, 512, 0, stream>>>(xn, Wo, P);
    // ln2 with fold: h += P0..P3+bo, then LN -> xn
    ln_fold4<<<M_, 256, 0, stream>>>(h, P, bo + l * D_,
                                     ln2_g + l * D_, ln2_b + l * D_, xn);
    // fc1 = gelu(xn @ Wf1T)   (8-phase 256x128, 256 blocks)
    gemm8n_fc1<<<256, 512, 0, stream>>>(xn, Wf1, S);
    // fc2 split-K=4 -> f32 partials P (folded by next fused LN)
    gemm8n_fc2<<<256, 512, 0, stream>>>(S, Wf2, P);
  }

  // fused: final LN (folds layer-3 partials) + wout transpose; then logits
  convwout_ln<<<10048, 256, 0, stream>>>(wout, WoutT, h, P, fn_g, fn_b, xn);
  gemm8_logits<<<1000, 512, 0, stream>>>(xn, WoutT, bout, out);
}